// Round 1
// baseline (57.827 us; speedup 1.0000x reference)
//
#include <hip/hip_runtime.h>
#include <hip/hip_fp16.h>

#define NB 16384     // batch rows
#define ND 256       // d_in (GEMM K)
#define NH 1024      // hidden (GEMM N)
#define NK 16        // sparse fan-in

using f16x8 = __attribute__((ext_vector_type(8))) _Float16;
using f16x4 = __attribute__((ext_vector_type(4))) _Float16;
using f32x4 = __attribute__((ext_vector_type(4))) float;

__device__ __forceinline__ float fast_tanh(float x) {
    // tanh(x) = 1 - 2/(exp(2x)+1); v_exp + v_rcp, ~1ulp each. Saturates correctly at +-inf.
    float e = __expf(2.0f * x);
    return 1.0f - 2.0f * __builtin_amdgcn_rcpf(e + 1.0f);
}

// ---------------------------------------------------------------------------
// Kernel 1: scatter w1 into dense W[h][d] (f16). One 64-thread group per h row,
// each thread owns 4 d-columns; idx/w1 reads are wave-uniform (scalar loads).
// Duplicate indices accumulate in f32 before the single f16 convert.
// ---------------------------------------------------------------------------
__global__ __launch_bounds__(256) void build_w_kernel(
        const int* __restrict__ idx, const float* __restrict__ w1,
        _Float16* __restrict__ W) {
    int t = blockIdx.x * 256 + threadIdx.x;      // 65536 threads total
    int h = t >> 6;
    int d0 = (t & 63) << 2;
    float a0 = 0.f, a1 = 0.f, a2 = 0.f, a3 = 0.f;
#pragma unroll
    for (int k = 0; k < NK; ++k) {
        int iv = idx[h * NK + k];
        float wv = w1[h * NK + k];
        int r = iv - d0;
        if (r == 0) a0 += wv;
        if (r == 1) a1 += wv;
        if (r == 2) a2 += wv;
        if (r == 3) a3 += wv;
    }
    f16x4 o;
    o[0] = (_Float16)a0; o[1] = (_Float16)a1; o[2] = (_Float16)a2; o[3] = (_Float16)a3;
    *reinterpret_cast<f16x4*>(&W[h * ND + d0]) = o;
}

// ---------------------------------------------------------------------------
// Kernel 2: fused GEMM  pre = x @ W^T  (M=16384, N=1024, K=256, f16 MFMA,
// f32 accum) + epilogue tanh(pre+b1)*w2 reduced over the block's 128 h-cols,
// atomicAdd per-row partials into accum[].
// Tile: BM=128, BN=128, BK=64. 256 threads = 4 waves (2x2), wave tile 64x64.
// LDS: lA/lB [128 rows][64 k] f16, XOR-swizzled 16B chunks: c ^= (row&7).
// ---------------------------------------------------------------------------
__global__ __launch_bounds__(256) void gemm_kernel(
        const float* __restrict__ x, const _Float16* __restrict__ W,
        const float* __restrict__ b1, const float* __restrict__ w2,
        float* __restrict__ accum) {
    __shared__ _Float16 lA[128 * 64];
    __shared__ _Float16 lB[128 * 64];

    const int gm0 = blockIdx.x * 128;
    const int gn0 = blockIdx.y * 128;
    const int t = threadIdx.x;
    const int lane = t & 63;
    const int wid = t >> 6;
    const int wm = wid >> 1;      // wave M index (0..1)
    const int wn = wid & 1;       // wave N index (0..1)

    // staging assignment: thread -> (row, 32-wide k half)
    const int sr = t >> 1;        // 0..127
    const int sh = t & 1;         // 0..1
    const float*    gA = x + (size_t)(gm0 + sr) * ND + sh * 32;
    const _Float16* gB = W + (size_t)(gn0 + sr) * ND + sh * 32;

    float4 ra[8];   // 32 f32 of x
    uint4  rb[4];   // 32 f16 of W

    f32x4 acc[4][4];
#pragma unroll
    for (int i = 0; i < 4; ++i)
#pragma unroll
        for (int j = 0; j < 4; ++j)
            acc[i][j] = f32x4{0.f, 0.f, 0.f, 0.f};

    const int rsw = (sr & 7);

    // prologue: load K-step 0
    {
        const float4* pa = reinterpret_cast<const float4*>(gA);
        const uint4*  pb = reinterpret_cast<const uint4*>(gB);
#pragma unroll
        for (int j = 0; j < 8; ++j) ra[j] = pa[j];
#pragma unroll
        for (int j = 0; j < 4; ++j) rb[j] = pb[j];
    }

#pragma unroll
    for (int s = 0; s < 4; ++s) {
        if (s > 0) __syncthreads();   // previous compute done before overwrite
        // cvt + swizzled ds_write
#pragma unroll
        for (int q = 0; q < 4; ++q) {
            int c = sh * 4 + q;
            f16x8 v;
            v[0] = (_Float16)ra[2 * q].x;     v[1] = (_Float16)ra[2 * q].y;
            v[2] = (_Float16)ra[2 * q].z;     v[3] = (_Float16)ra[2 * q].w;
            v[4] = (_Float16)ra[2 * q + 1].x; v[5] = (_Float16)ra[2 * q + 1].y;
            v[6] = (_Float16)ra[2 * q + 1].z; v[7] = (_Float16)ra[2 * q + 1].w;
            int off = sr * 64 + ((c ^ rsw) << 3);
            *reinterpret_cast<f16x8*>(&lA[off]) = v;
            *reinterpret_cast<uint4*>(&lB[off]) = rb[q];
        }
        __syncthreads();

        // issue next K-step's global loads before compute (overlap, T14)
        if (s < 3) {
            const float4* pa = reinterpret_cast<const float4*>(gA + (s + 1) * 64);
            const uint4*  pb = reinterpret_cast<const uint4*>(gB + (s + 1) * 64);
#pragma unroll
            for (int j = 0; j < 8; ++j) ra[j] = pa[j];
#pragma unroll
            for (int j = 0; j < 4; ++j) rb[j] = pb[j];
        }

        // compute this K-step: 2 MFMA k-blocks of 32
#pragma unroll
        for (int kb = 0; kb < 2; ++kb) {
            const int cbase = kb * 4 + (lane >> 4);
            f16x8 af[4], bf[4];
#pragma unroll
            for (int mi = 0; mi < 4; ++mi) {
                int row = wm * 64 + mi * 16 + (lane & 15);
                af[mi] = *reinterpret_cast<const f16x8*>(&lA[row * 64 + ((cbase ^ (row & 7)) << 3)]);
            }
#pragma unroll
            for (int ni = 0; ni < 4; ++ni) {
                int row = wn * 64 + ni * 16 + (lane & 15);
                bf[ni] = *reinterpret_cast<const f16x8*>(&lB[row * 64 + ((cbase ^ (row & 7)) << 3)]);
            }
#pragma unroll
            for (int mi = 0; mi < 4; ++mi)
#pragma unroll
                for (int ni = 0; ni < 4; ++ni)
                    acc[mi][ni] = __builtin_amdgcn_mfma_f32_16x16x32_f16(
                        af[mi], bf[ni], acc[mi][ni], 0, 0, 0);
        }
    }

    // ---- fused epilogue: tanh(pre+b1)*w2, reduce over this block's 128 cols ----
    const int cl = lane & 15;
    const int rg = lane >> 4;
    float rowpart[4][4];
#pragma unroll
    for (int mi = 0; mi < 4; ++mi)
#pragma unroll
        for (int r = 0; r < 4; ++r) rowpart[mi][r] = 0.f;

#pragma unroll
    for (int ni = 0; ni < 4; ++ni) {
        int col = gn0 + wn * 64 + ni * 16 + cl;
        float w2v = w2[col];
        float b1v = b1[col];
#pragma unroll
        for (int mi = 0; mi < 4; ++mi)
#pragma unroll
            for (int r = 0; r < 4; ++r)
                rowpart[mi][r] += fast_tanh(acc[mi][ni][r] + b1v) * w2v;
    }

    // reduce over the 16 col-lanes of each lane group, then one atomic per row
#pragma unroll
    for (int mi = 0; mi < 4; ++mi)
#pragma unroll
        for (int r = 0; r < 4; ++r) {
            float v = rowpart[mi][r];
            v += __shfl_xor(v, 1);
            v += __shfl_xor(v, 2);
            v += __shfl_xor(v, 4);
            v += __shfl_xor(v, 8);
            if (cl == 0) {
                int row = gm0 + wm * 64 + mi * 16 + rg * 4 + r;
                atomicAdd(&accum[row], v);
            }
        }
}

// ---------------------------------------------------------------------------
// Kernel 3: out[b] = tanh(accum[b] + b2)
// ---------------------------------------------------------------------------
__global__ __launch_bounds__(256) void finalize_kernel(
        const float* __restrict__ accum, const float* __restrict__ b2,
        float* __restrict__ out) {
    int i = blockIdx.x * 256 + threadIdx.x;
    out[i] = fast_tanh(accum[i] + b2[0]);
}

extern "C" void kernel_launch(void* const* d_in, const int* in_sizes, int n_in,
                              void* d_out, int out_size, void* d_ws, size_t ws_size,
                              hipStream_t stream) {
    const float* x   = (const float*)d_in[0];
    const int*   idx = (const int*)d_in[1];    // per harness doc: integer -> const int*
    const float* w1  = (const float*)d_in[2];
    const float* b1  = (const float*)d_in[3];
    const float* w2  = (const float*)d_in[4];
    const float* b2  = (const float*)d_in[5];
    float* out = (float*)d_out;

    // ws layout: [0,64KB) f32 accum[16384]; [64KB,576KB) f16 W[1024][256]
    float*     accum = (float*)d_ws;
    _Float16*  W     = (_Float16*)((char*)d_ws + (size_t)NB * sizeof(float));

    hipMemsetAsync(accum, 0, (size_t)NB * sizeof(float), stream);
    build_w_kernel<<<(NH * 64) / 256, 256, 0, stream>>>(idx, w1, W);
    gemm_kernel<<<dim3(NB / 128, NH / 128), 256, 0, stream>>>(x, W, b1, w2, accum);
    finalize_kernel<<<NB / 256, 256, 0, stream>>>(accum, b2, out);
}

// Round 2
// 31.817 us; speedup vs baseline: 1.8175x; 1.8175x over previous
//
#include <hip/hip_runtime.h>
#include <hip/hip_fp16.h>

#define NB 16384     // batch rows
#define ND 256       // d_in (GEMM K)
#define NH 1024      // hidden (GEMM N)
#define NK 16        // sparse fan-in

using f16x8 = __attribute__((ext_vector_type(8))) _Float16;
using f16x4 = __attribute__((ext_vector_type(4))) _Float16;
using f32x4 = __attribute__((ext_vector_type(4))) float;

__device__ __forceinline__ float fast_tanh(float x) {
    // tanh(x) = 1 - 2/(exp(2x)+1)
    float e = __expf(2.0f * x);
    return 1.0f - 2.0f * __builtin_amdgcn_rcpf(e + 1.0f);
}

// ---------------------------------------------------------------------------
// Kernel 1: scatter w1 into dense W[h][d] (f16). One 64-thread group per h,
// each thread owns 4 d-columns; idx/w1 reads are wave-uniform.
// Duplicate indices accumulate in f32 before the single f16 convert.
// ---------------------------------------------------------------------------
__global__ __launch_bounds__(256) void build_w_kernel(
        const int* __restrict__ idx, const float* __restrict__ w1,
        _Float16* __restrict__ W) {
    int t = blockIdx.x * 256 + threadIdx.x;      // 65536 threads total
    int h = t >> 6;
    int d0 = (t & 63) << 2;
    float a0 = 0.f, a1 = 0.f, a2 = 0.f, a3 = 0.f;
#pragma unroll
    for (int k = 0; k < NK; ++k) {
        int iv = idx[h * NK + k];
        float wv = w1[h * NK + k];
        int r = iv - d0;
        if (r == 0) a0 += wv;
        if (r == 1) a1 += wv;
        if (r == 2) a2 += wv;
        if (r == 3) a3 += wv;
    }
    f16x4 o;
    o[0] = (_Float16)a0; o[1] = (_Float16)a1; o[2] = (_Float16)a2; o[3] = (_Float16)a3;
    *reinterpret_cast<f16x4*>(&W[h * ND + d0]) = o;
}

// ---------------------------------------------------------------------------
// Kernel 2: fully-fused. Block = 64 rows x ALL 1024 cols; 8 waves, wave w
// owns cols [w*128, w*128+128) as 8 chunks of 16. A (x tile, f16) staged in
// swizzled LDS once, then each wave's 32 A-fragments held in registers
// (128 VGPR) -> main loop is barrier-free. B fragments loaded straight from
// global (W is L2-resident, 512 KB), double-buffered one chunk ahead.
// Epilogue per chunk: tanh(acc+b1)*w2 accumulated into per-row partials;
// final shfl + LDS reduce, tanh, direct store. No atomics.
// ---------------------------------------------------------------------------
__global__ __launch_bounds__(512, 2) void fused_kernel(
        const float* __restrict__ x, const _Float16* __restrict__ W,
        const float* __restrict__ b1, const float* __restrict__ w2,
        const float* __restrict__ b2, float* __restrict__ out) {
    __shared__ _Float16 lA[64 * 256];   // 32 KB, 16B chunks swizzled: c ^= (r&7)
    __shared__ float red[8 * 64];       // 2 KB cross-wave reduction

    const int t = threadIdx.x;
    const int lane = t & 63;
    const int w = t >> 6;               // wave 0..7
    const int gm0 = blockIdx.x * 64;

    // ---- stage x tile (64x256 f32) -> LDS f16, swizzled ----
    {
        int r = t >> 3;                 // 0..63
        int sub = t & 7;                // 0..7, 32 f32 each
        const float4* src = reinterpret_cast<const float4*>(
            x + (size_t)(gm0 + r) * ND + sub * 32);
        float4 v[8];
#pragma unroll
        for (int j = 0; j < 8; ++j) v[j] = src[j];
#pragma unroll
        for (int q = 0; q < 4; ++q) {
            int c = sub * 4 + q;        // 16B chunk index 0..31
            f16x8 h;
            h[0] = (_Float16)v[2*q].x;   h[1] = (_Float16)v[2*q].y;
            h[2] = (_Float16)v[2*q].z;   h[3] = (_Float16)v[2*q].w;
            h[4] = (_Float16)v[2*q+1].x; h[5] = (_Float16)v[2*q+1].y;
            h[6] = (_Float16)v[2*q+1].z; h[7] = (_Float16)v[2*q+1].w;
            int a16 = r * 32 + (c ^ (r & 7));
            *reinterpret_cast<f16x8*>(&lA[a16 * 8]) = h;
        }
    }
    __syncthreads();

    const int ml = lane & 15;           // M row lane / N col lane
    const int kg = lane >> 4;           // k-group 0..3

    // ---- pull this wave's A fragments into registers (held for whole kernel)
    f16x8 af[4][8];                     // [mi][ks]  (rows mi*16+ml, k ks*32+kg*8)
#pragma unroll
    for (int mi = 0; mi < 4; ++mi)
#pragma unroll
        for (int ks = 0; ks < 8; ++ks) {
            int r = mi * 16 + ml;
            int c = ks * 4 + kg;
            af[mi][ks] = *reinterpret_cast<const f16x8*>(
                &lA[(r * 32 + (c ^ (r & 7))) * 8]);
        }

    // ---- main loop: 8 n-chunks of 16 cols, B from global, double-buffered
    const _Float16* gB = W + (size_t)(w * 128 + ml) * ND + kg * 8;

    float rowpart[4][4];
#pragma unroll
    for (int mi = 0; mi < 4; ++mi)
#pragma unroll
        for (int r4 = 0; r4 < 4; ++r4) rowpart[mi][r4] = 0.f;

    uint4 bfr[2][8];
#pragma unroll
    for (int ks = 0; ks < 8; ++ks)
        bfr[0][ks] = *reinterpret_cast<const uint4*>(gB + ks * 32);

#pragma unroll
    for (int nc = 0; nc < 8; ++nc) {
        // prefetch next chunk's B fragments
        if (nc < 7) {
            const _Float16* p = gB + (size_t)(nc + 1) * 16 * ND;
#pragma unroll
            for (int ks = 0; ks < 8; ++ks)
                bfr[(nc + 1) & 1][ks] = *reinterpret_cast<const uint4*>(p + ks * 32);
        }
        int col = w * 128 + nc * 16 + ml;
        float b1v = b1[col];
        float w2v = w2[col];

        f32x4 acc[4];
#pragma unroll
        for (int mi = 0; mi < 4; ++mi) acc[mi] = f32x4{0.f, 0.f, 0.f, 0.f};

#pragma unroll
        for (int ks = 0; ks < 8; ++ks) {
            f16x8 bf = *reinterpret_cast<const f16x8*>(&bfr[nc & 1][ks]);
#pragma unroll
            for (int mi = 0; mi < 4; ++mi)
                acc[mi] = __builtin_amdgcn_mfma_f32_16x16x32_f16(
                    af[mi][ks], bf, acc[mi], 0, 0, 0);
        }

        // epilogue: tanh(pre+b1)*w2 into row partials (16 vals/lane)
#pragma unroll
        for (int mi = 0; mi < 4; ++mi)
#pragma unroll
            for (int r4 = 0; r4 < 4; ++r4)
                rowpart[mi][r4] += fast_tanh(acc[mi][r4] + b1v) * w2v;
    }

    // ---- reduce over the 16 col-lanes of each group ----
#pragma unroll
    for (int mi = 0; mi < 4; ++mi)
#pragma unroll
        for (int r4 = 0; r4 < 4; ++r4) {
            float v = rowpart[mi][r4];
            v += __shfl_xor(v, 1);
            v += __shfl_xor(v, 2);
            v += __shfl_xor(v, 4);
            v += __shfl_xor(v, 8);
            rowpart[mi][r4] = v;
        }
    if (ml == 0) {
#pragma unroll
        for (int mi = 0; mi < 4; ++mi)
#pragma unroll
            for (int r4 = 0; r4 < 4; ++r4)
                red[w * 64 + mi * 16 + kg * 4 + r4] = rowpart[mi][r4];
    }
    __syncthreads();

    // ---- cross-wave sum + final tanh + store (one thread per row) ----
    if (t < 64) {
        float s = 0.f;
#pragma unroll
        for (int j = 0; j < 8; ++j) s += red[j * 64 + t];
        out[gm0 + t] = fast_tanh(s + b2[0]);
    }
}

extern "C" void kernel_launch(void* const* d_in, const int* in_sizes, int n_in,
                              void* d_out, int out_size, void* d_ws, size_t ws_size,
                              hipStream_t stream) {
    const float* x   = (const float*)d_in[0];
    const int*   idx = (const int*)d_in[1];
    const float* w1  = (const float*)d_in[2];
    const float* b1  = (const float*)d_in[3];
    const float* w2  = (const float*)d_in[4];
    const float* b2  = (const float*)d_in[5];
    float* out = (float*)d_out;

    _Float16* W = (_Float16*)d_ws;      // 512 KB dense W[1024][256] f16

    build_w_kernel<<<(NH * 64) / 256, 256, 0, stream>>>(idx, w1, W);
    fused_kernel<<<NB / 64, 512, 0, stream>>>(x, W, b1, w2, b2, out);
}

// Round 3
// 26.185 us; speedup vs baseline: 2.2084x; 1.2151x over previous
//
#include <hip/hip_runtime.h>
#include <hip/hip_fp16.h>

#define NB 16384     // batch rows
#define ND 256       // d_in (GEMM K)
#define NH 1024      // hidden (GEMM N)
#define NK 16        // sparse fan-in

using f16x8 = __attribute__((ext_vector_type(8))) _Float16;
using f32x4 = __attribute__((ext_vector_type(4))) float;

__device__ __forceinline__ float fast_tanh(float x) {
    // tanh(x) = 1 - 2/(exp(2x)+1)
    float e = __expf(2.0f * x);
    return 1.0f - 2.0f * __builtin_amdgcn_rcpf(e + 1.0f);
}

// ---------------------------------------------------------------------------
// Kernel 1: scatter w1 into FRAGMENT-ORDERED dense Wf (f16).
// Fragment order: for 16-col chunk c (cols/h 16c..16c+15), k-slice ks (k =
// 32ks..32ks+31), MFMA lane l = kg*16+ml holds W[col=16c+ml][k=32ks+8kg..+8].
// Flat: Wf[((c*8+ks)*64 + l)*8 + e]  -> each B-fragment load is one
// contiguous 1KB block (lane*16B), perfectly coalesced.
// One thread per (h, 8-elem k-group): h = t>>5, g = t&31, d in [8g, 8g+8).
// ---------------------------------------------------------------------------
__global__ __launch_bounds__(256) void build_w_kernel(
        const int* __restrict__ idx, const float* __restrict__ w1,
        _Float16* __restrict__ Wf) {
    int t = blockIdx.x * 256 + threadIdx.x;      // NH*32 = 32768 threads
    int h = t >> 5;
    int g = t & 31;
    int d0 = g << 3;
    float a[8];
#pragma unroll
    for (int e = 0; e < 8; ++e) a[e] = 0.f;
#pragma unroll
    for (int k = 0; k < NK; ++k) {
        int iv = idx[h * NK + k];
        float wv = w1[h * NK + k];
#pragma unroll
        for (int e = 0; e < 8; ++e)
            if (iv == d0 + e) a[e] += wv;        // static index, predicated add
    }
    int c  = h >> 4;
    int ml = h & 15;
    int ks = g >> 2;
    int kg = g & 3;
    size_t off = (((size_t)(c * 8 + ks)) * 64 + kg * 16 + ml) * 8;
    f16x8 o;
#pragma unroll
    for (int e = 0; e < 8; ++e) o[e] = (_Float16)a[e];
    *reinterpret_cast<f16x8*>(&Wf[off]) = o;
}

// ---------------------------------------------------------------------------
// Kernel 2: fully-fused. Block = 64 rows x ALL 1024 cols; 8 waves, wave w
// owns cols [w*128, w*128+128) = 8 chunks of 16. A held in registers
// (af[4][8], 128 VGPR) after one swizzled-LDS stage of x. B streamed from
// fragment-ordered Wf (L2-resident) with half-chunk ping-pong (bA/bB, 32
// VGPR). Epilogue per chunk: tanh(acc+b1)*w2 into row partials; final
// shfl + LDS reduce, tanh, store. No atomics, barrier-free main loop.
// ---------------------------------------------------------------------------
__global__ __launch_bounds__(512, 2) void fused_kernel(
        const float* __restrict__ x, const _Float16* __restrict__ Wf,
        const float* __restrict__ b1, const float* __restrict__ w2,
        const float* __restrict__ b2, float* __restrict__ out) {
    __shared__ _Float16 lA[64 * 256];   // 32 KB, 16B chunks swizzled: c ^= (r&7)
    __shared__ float red[8 * 64];       // 2 KB cross-wave reduction

    const int t = threadIdx.x;
    const int lane = t & 63;
    const int w = t >> 6;               // wave 0..7
    const int gm0 = blockIdx.x * 64;

    // ---- stage x tile (64x256 f32) -> LDS f16, swizzled ----
    {
        int r = t >> 3;                 // 0..63
        int sub = t & 7;                // 0..7, 32 f32 each
        const float4* src = reinterpret_cast<const float4*>(
            x + (size_t)(gm0 + r) * ND + sub * 32);
        float4 v[8];
#pragma unroll
        for (int j = 0; j < 8; ++j) v[j] = src[j];
#pragma unroll
        for (int q = 0; q < 4; ++q) {
            int c = sub * 4 + q;        // 16B chunk index 0..31
            f16x8 hh;
            hh[0] = (_Float16)v[2*q].x;   hh[1] = (_Float16)v[2*q].y;
            hh[2] = (_Float16)v[2*q].z;   hh[3] = (_Float16)v[2*q].w;
            hh[4] = (_Float16)v[2*q+1].x; hh[5] = (_Float16)v[2*q+1].y;
            hh[6] = (_Float16)v[2*q+1].z; hh[7] = (_Float16)v[2*q+1].w;
            int a16 = r * 32 + (c ^ (r & 7));
            *reinterpret_cast<f16x8*>(&lA[a16 * 8]) = hh;
        }
    }
    __syncthreads();

    const int ml = lane & 15;
    const int kg = lane >> 4;

    // ---- pull this wave's A fragments into registers (whole kernel) ----
    f16x8 af[4][8];                     // [mi][ks]
#pragma unroll
    for (int mi = 0; mi < 4; ++mi)
#pragma unroll
        for (int ks = 0; ks < 8; ++ks) {
            int r = mi * 16 + ml;
            int c = ks * 4 + kg;
            af[mi][ks] = *reinterpret_cast<const f16x8*>(
                &lA[(r * 32 + (c ^ (r & 7))) * 8]);
        }

    // ---- preload this wave's b1/w2 (8 chunks) ----
    float b1v[8], w2v[8];
#pragma unroll
    for (int nc = 0; nc < 8; ++nc) {
        int col = w * 128 + nc * 16 + ml;
        b1v[nc] = b1[col];
        w2v[nc] = w2[col];
    }

    // ---- main loop over 8 n-chunks, B from fragment-ordered Wf ----
    // fragment block (c, ks) lives at Wf + (c*8+ks)*512, lane offset lane*8
    const _Float16* gB = Wf + (size_t)w * 32768 + (size_t)lane * 8;

    float rowpart[4][4];
#pragma unroll
    for (int mi = 0; mi < 4; ++mi)
#pragma unroll
        for (int r4 = 0; r4 < 4; ++r4) rowpart[mi][r4] = 0.f;

    f16x8 bA[4], bB[4];
#pragma unroll
    for (int ks = 0; ks < 4; ++ks)
        bA[ks] = *reinterpret_cast<const f16x8*>(gB + ks * 512);

#pragma unroll
    for (int nc = 0; nc < 8; ++nc) {
        f32x4 acc[4];
#pragma unroll
        for (int mi = 0; mi < 4; ++mi) acc[mi] = f32x4{0.f, 0.f, 0.f, 0.f};

        // prefetch second half of this chunk
#pragma unroll
        for (int ks = 0; ks < 4; ++ks)
            bB[ks] = *reinterpret_cast<const f16x8*>(gB + (nc * 8 + 4 + ks) * 512);
        // compute first half
#pragma unroll
        for (int ks = 0; ks < 4; ++ks)
#pragma unroll
            for (int mi = 0; mi < 4; ++mi)
                acc[mi] = __builtin_amdgcn_mfma_f32_16x16x32_f16(
                    af[mi][ks], bA[ks], acc[mi], 0, 0, 0);
        // prefetch next chunk's first half
        if (nc < 7) {
#pragma unroll
            for (int ks = 0; ks < 4; ++ks)
                bA[ks] = *reinterpret_cast<const f16x8*>(gB + ((nc + 1) * 8 + ks) * 512);
        }
        // compute second half
#pragma unroll
        for (int ks = 0; ks < 4; ++ks)
#pragma unroll
            for (int mi = 0; mi < 4; ++mi)
                acc[mi] = __builtin_amdgcn_mfma_f32_16x16x32_f16(
                    af[mi][4 + ks], bB[ks], acc[mi], 0, 0, 0);

        // epilogue: tanh(pre+b1)*w2 into row partials
#pragma unroll
        for (int mi = 0; mi < 4; ++mi)
#pragma unroll
            for (int r4 = 0; r4 < 4; ++r4)
                rowpart[mi][r4] += fast_tanh(acc[mi][r4] + b1v[nc]) * w2v[nc];
    }

    // ---- reduce over the 16 col-lanes of each group ----
#pragma unroll
    for (int mi = 0; mi < 4; ++mi)
#pragma unroll
        for (int r4 = 0; r4 < 4; ++r4) {
            float v = rowpart[mi][r4];
            v += __shfl_xor(v, 1);
            v += __shfl_xor(v, 2);
            v += __shfl_xor(v, 4);
            v += __shfl_xor(v, 8);
            rowpart[mi][r4] = v;
        }
    if (ml == 0) {
#pragma unroll
        for (int mi = 0; mi < 4; ++mi)
#pragma unroll
            for (int r4 = 0; r4 < 4; ++r4)
                red[w * 64 + mi * 16 + kg * 4 + r4] = rowpart[mi][r4];
    }
    __syncthreads();

    // ---- cross-wave sum + final tanh + store ----
    if (t < 64) {
        float s = 0.f;
#pragma unroll
        for (int j = 0; j < 8; ++j) s += red[j * 64 + t];
        out[gm0 + t] = fast_tanh(s + b2[0]);
    }
}

extern "C" void kernel_launch(void* const* d_in, const int* in_sizes, int n_in,
                              void* d_out, int out_size, void* d_ws, size_t ws_size,
                              hipStream_t stream) {
    const float* x   = (const float*)d_in[0];
    const int*   idx = (const int*)d_in[1];
    const float* w1  = (const float*)d_in[2];
    const float* b1  = (const float*)d_in[3];
    const float* w2  = (const float*)d_in[4];
    const float* b2  = (const float*)d_in[5];
    float* out = (float*)d_out;

    _Float16* Wf = (_Float16*)d_ws;     // 512 KB fragment-ordered W

    build_w_kernel<<<(NH * 32) / 256, 256, 0, stream>>>(idx, w1, Wf);
    fused_kernel<<<NB / 64, 512, 0, stream>>>(x, Wf, b1, w2, b2, out);
}

// Round 4
// 22.338 us; speedup vs baseline: 2.5887x; 1.1722x over previous
//
#include <hip/hip_runtime.h>
#include <hip/hip_fp16.h>

#define NB 16384     // batch rows
#define ND 256       // d_in (GEMM K)
#define NH 1024      // hidden (GEMM N)
#define NK 16        // sparse fan-in

using f16x8 = __attribute__((ext_vector_type(8))) _Float16;
using f32x4 = __attribute__((ext_vector_type(4))) float;

__device__ __forceinline__ float fast_tanh(float x) {
    // tanh(x) = 1 - 2/(exp(2x)+1); 2 trans insts (v_exp, v_rcp)
    float e = __expf(2.0f * x);
    return 1.0f - 2.0f * __builtin_amdgcn_rcpf(e + 1.0f);
}

// ---------------------------------------------------------------------------
// Kernel 1: scatter w1 into FRAGMENT-ORDERED dense Wf (f16).
// Fragment block (c, ks): 16-col chunk c, k-slice ks (k = 32ks..32ks+31).
// MFMA lane l = kg*16+ml holds W[col=16c+ml][k=32ks+8kg .. +8].
// Flat: Wf[((c*8+ks)*64 + l)*8 + e] -> each B-fragment load is one contiguous
// 1KB block (lane*16B), perfectly coalesced.
// ---------------------------------------------------------------------------
__global__ __launch_bounds__(256) void build_w_kernel(
        const int* __restrict__ idx, const float* __restrict__ w1,
        _Float16* __restrict__ Wf) {
    int t = blockIdx.x * 256 + threadIdx.x;      // NH*32 = 32768 threads
    int h = t >> 5;
    int g = t & 31;
    int d0 = g << 3;
    float a[8];
#pragma unroll
    for (int e = 0; e < 8; ++e) a[e] = 0.f;
#pragma unroll
    for (int k = 0; k < NK; ++k) {
        int iv = idx[h * NK + k];
        float wv = w1[h * NK + k];
#pragma unroll
        for (int e = 0; e < 8; ++e)
            if (iv == d0 + e) a[e] += wv;        // static index, predicated add
    }
    int c  = h >> 4;
    int ml = h & 15;
    int ks = g >> 2;
    int kg = g & 3;
    size_t off = (((size_t)(c * 8 + ks)) * 64 + kg * 16 + ml) * 8;
    f16x8 o;
#pragma unroll
    for (int e = 0; e < 8; ++e) o[e] = (_Float16)a[e];
    *reinterpret_cast<f16x8*>(&Wf[off]) = o;
}

// ---------------------------------------------------------------------------
// Kernel 2: fully-fused. Block = 64 rows x ALL 1024 cols; 8 waves, wave w
// owns cols [w*128, w*128+128) = 8 chunks of 16. A held in registers
// (af[4][8], 128 VGPR) after one swizzled-LDS stage of x. B streamed from
// fragment-ordered Wf (L2-resident) via a runtime unroll-1 loop with two
// incremented bases (imm offsets <= 3072B) and full-chunk-ahead prefetch.
// Epilogue per chunk: tanh(acc+b1)*w2 into row partials; final shfl + LDS
// reduce, tanh, store. No atomics, barrier-free main loop.
// ---------------------------------------------------------------------------
__global__ __launch_bounds__(512, 2) void fused_kernel(
        const float* __restrict__ x, const _Float16* __restrict__ Wf,
        const float* __restrict__ b1, const float* __restrict__ w2,
        const float* __restrict__ b2, float* __restrict__ out) {
    __shared__ _Float16 lA[64 * 256];   // 32 KB, 16B chunks swizzled: c ^= (r&7)
    __shared__ float red[8 * 64];       // 2 KB cross-wave reduction

    const int t = threadIdx.x;
    const int lane = t & 63;
    const int w = t >> 6;               // wave 0..7
    const int gm0 = blockIdx.x * 64;
    const int ml = lane & 15;
    const int kg = lane >> 4;

    // ---- issue x loads first (HBM latency), then chunk-0 B loads (L2) ----
    const int sr  = t >> 3;             // 0..63 staging row
    const int sub = t & 7;              // 32 f32 each
    const float4* xsrc = reinterpret_cast<const float4*>(
        x + (size_t)(gm0 + sr) * ND + sub * 32);
    float4 v[8];
#pragma unroll
    for (int j = 0; j < 8; ++j) v[j] = xsrc[j];

    // B fragment stream base for this wave (fragment-ordered Wf)
    const _Float16* gB = Wf + (size_t)w * 32768 + (size_t)lane * 8;
    f16x8 bA[4], bB[4];
#pragma unroll
    for (int ks = 0; ks < 4; ++ks)
        bA[ks] = *reinterpret_cast<const f16x8*>(gB + ks * 512);
#pragma unroll
    for (int ks = 0; ks < 4; ++ks)
        bB[ks] = *reinterpret_cast<const f16x8*>(gB + 2048 + ks * 512);

    // ---- stage x tile (64x256) -> LDS f16, swizzled ----
#pragma unroll
    for (int q = 0; q < 4; ++q) {
        int c = sub * 4 + q;            // 16B chunk index 0..31
        f16x8 hh;
        hh[0] = (_Float16)v[2*q].x;   hh[1] = (_Float16)v[2*q].y;
        hh[2] = (_Float16)v[2*q].z;   hh[3] = (_Float16)v[2*q].w;
        hh[4] = (_Float16)v[2*q+1].x; hh[5] = (_Float16)v[2*q+1].y;
        hh[6] = (_Float16)v[2*q+1].z; hh[7] = (_Float16)v[2*q+1].w;
        int a16 = sr * 32 + (c ^ (sr & 7));
        *reinterpret_cast<f16x8*>(&lA[a16 * 8]) = hh;
    }
    __syncthreads();

    // ---- pull this wave's A fragments into registers (whole kernel) ----
    f16x8 af[4][8];                     // [mi][ks]
#pragma unroll
    for (int mi = 0; mi < 4; ++mi)
#pragma unroll
        for (int ks = 0; ks < 8; ++ks) {
            int r = mi * 16 + ml;
            int c = ks * 4 + kg;
            af[mi][ks] = *reinterpret_cast<const f16x8*>(
                &lA[(r * 32 + (c ^ (r & 7))) * 8]);
        }

    float rowpart[4][4];
#pragma unroll
    for (int mi = 0; mi < 4; ++mi)
#pragma unroll
        for (int r4 = 0; r4 < 4; ++r4) rowpart[mi][r4] = 0.f;

    // ---- main loop: runtime loop, two advancing bases, imm offsets <=3072B
    const _Float16* pb0 = gB + 4096;        // next chunk, frags 0..3
    const _Float16* pb1 = gB + 4096 + 2048; // next chunk, frags 4..7
    const float* b1p = b1 + w * 128 + ml;
    const float* w2p = w2 + w * 128 + ml;

#pragma unroll 1
    for (int nc = 0; nc < 8; ++nc) {
        f32x4 acc[4];
#pragma unroll
        for (int mi = 0; mi < 4; ++mi) acc[mi] = f32x4{0.f, 0.f, 0.f, 0.f};

        // compute first half (bA), then prefetch next chunk's first half
#pragma unroll
        for (int ks = 0; ks < 4; ++ks)
#pragma unroll
            for (int mi = 0; mi < 4; ++mi)
                acc[mi] = __builtin_amdgcn_mfma_f32_16x16x32_f16(
                    af[mi][ks], bA[ks], acc[mi], 0, 0, 0);
        if (nc != 7) {
#pragma unroll
            for (int ks = 0; ks < 4; ++ks)
                bA[ks] = *reinterpret_cast<const f16x8*>(pb0 + ks * 512);
        }

        // compute second half (bB), then prefetch next chunk's second half
#pragma unroll
        for (int ks = 0; ks < 4; ++ks)
#pragma unroll
            for (int mi = 0; mi < 4; ++mi)
                acc[mi] = __builtin_amdgcn_mfma_f32_16x16x32_f16(
                    af[mi][4 + ks], bB[ks], acc[mi], 0, 0, 0);
        if (nc != 7) {
#pragma unroll
            for (int ks = 0; ks < 4; ++ks)
                bB[ks] = *reinterpret_cast<const f16x8*>(pb1 + ks * 512);
        }
        pb0 += 4096;
        pb1 += 4096;

        // epilogue: tanh(pre+b1)*w2 into row partials (b1/w2 L1-hot)
        float b1v = b1p[nc * 16];
        float w2v = w2p[nc * 16];
#pragma unroll
        for (int mi = 0; mi < 4; ++mi)
#pragma unroll
            for (int r4 = 0; r4 < 4; ++r4)
                rowpart[mi][r4] += fast_tanh(acc[mi][r4] + b1v) * w2v;
    }

    // ---- reduce over the 16 col-lanes of each group ----
#pragma unroll
    for (int mi = 0; mi < 4; ++mi)
#pragma unroll
        for (int r4 = 0; r4 < 4; ++r4) {
            float vv = rowpart[mi][r4];
            vv += __shfl_xor(vv, 1);
            vv += __shfl_xor(vv, 2);
            vv += __shfl_xor(vv, 4);
            vv += __shfl_xor(vv, 8);
            rowpart[mi][r4] = vv;
        }
    if (ml == 0) {
#pragma unroll
        for (int mi = 0; mi < 4; ++mi)
#pragma unroll
            for (int r4 = 0; r4 < 4; ++r4)
                red[w * 64 + mi * 16 + kg * 4 + r4] = rowpart[mi][r4];
    }
    __syncthreads();

    // ---- cross-wave sum + final tanh + store ----
    if (t < 64) {
        float s = 0.f;
#pragma unroll
        for (int j = 0; j < 8; ++j) s += red[j * 64 + t];
        out[gm0 + t] = fast_tanh(s + b2[0]);
    }
}

extern "C" void kernel_launch(void* const* d_in, const int* in_sizes, int n_in,
                              void* d_out, int out_size, void* d_ws, size_t ws_size,
                              hipStream_t stream) {
    const float* x   = (const float*)d_in[0];
    const int*   idx = (const int*)d_in[1];
    const float* w1  = (const float*)d_in[2];
    const float* b1  = (const float*)d_in[3];
    const float* w2  = (const float*)d_in[4];
    const float* b2  = (const float*)d_in[5];
    float* out = (float*)d_out;

    _Float16* Wf = (_Float16*)d_ws;     // 512 KB fragment-ordered W

    build_w_kernel<<<(NH * 32) / 256, 256, 0, stream>>>(idx, w1, Wf);
    fused_kernel<<<NB / 64, 512, 0, stream>>>(x, Wf, b1, w2, b2, out);
}